// Round 7
// baseline (1765.251 us; speedup 1.0000x reference)
//
#include <hip/hip_runtime.h>

#define S_LEN 2048
#define DMODEL 2048
#define NH 16
#define NKV 4
#define HD 128
#define NE 8
#define FF 2048
#define QKV_N 3072   // (H + 2*KV) * HD

typedef __attribute__((ext_vector_type(8))) short short8;
typedef __attribute__((ext_vector_type(4))) float f32x4;

__device__ inline unsigned short f2bf(float f) {
  unsigned int u = __builtin_bit_cast(unsigned int, f);
  u += 0x7fffu + ((u >> 16) & 1u);
  return (unsigned short)(u >> 16);
}
__device__ inline float bf2f(unsigned short h) {
  unsigned int u = ((unsigned int)h) << 16;
  return __builtin_bit_cast(float, u);
}
__device__ inline void split2(float v, unsigned short& h, unsigned short& l) {
  h = f2bf(v);
  l = f2bf(v - bf2f(h));
}

// ======== LDS tile: [128 rows][32 k] bf16, XOR-quad swizzle (verified r3-r6) ========

__device__ inline void stage_rows(const unsigned short* __restrict__ src, int ld,
                                  long row0, int k0, unsigned short* dst) {
  int t = threadIdx.x;
  int r = t >> 2, q = t & 3;
  int s = (r ^ (r >> 2)) & 3;
  uint4 v0 = *(const uint4*)(src + (size_t)(row0 + r) * ld + k0 + q * 8);
  uint4 v1 = *(const uint4*)(src + (size_t)(row0 + r + 64) * ld + k0 + q * 8);
  *(uint4*)(dst + r * 32 + ((q ^ s) << 3)) = v0;
  *(uint4*)(dst + (r + 64) * 32 + ((q ^ s) << 3)) = v1;
}

__device__ inline void loadA2_rows(const unsigned short* __restrict__ src, int ld,
                                   long row0, int k0, uint4 va[2]) {
  int t = threadIdx.x;
  int r = t >> 2, q = t & 3;
  va[0] = *(const uint4*)(src + (size_t)(row0 + r) * ld + k0 + q * 8);
  va[1] = *(const uint4*)(src + (size_t)(row0 + r + 64) * ld + k0 + q * 8);
}
__device__ inline void loadA2_g(const unsigned short* __restrict__ src, int ld,
                                const int* __restrict__ toks, int nvalid, int k0,
                                uint4 va[2]) {
  int t = threadIdx.x;
  int r = t >> 2, q = t & 3;
#pragma unroll
  for (int rr = 0; rr < 2; rr++) {
    int row = r + rr * 64;
    uint4 v = make_uint4(0, 0, 0, 0);
    if (row < nvalid) v = *(const uint4*)(src + (size_t)toks[row] * ld + k0 + q * 8);
    va[rr] = v;
  }
}
__device__ inline void writeA2(const uint4 va[2], unsigned short* dst) {
  int t = threadIdx.x;
  int r = t >> 2, q = t & 3;
  int s = (r ^ (r >> 2)) & 3;
  *(uint4*)(dst + r * 32 + ((q ^ s) << 3)) = va[0];
  *(uint4*)(dst + (r + 64) * 32 + ((q ^ s) << 3)) = va[1];
}

// ---- async chunk staging: 8 KB pre-swizzled chunk -> LDS, verbatim ----
__device__ inline void gload16(const void* g, void* l) {
  __builtin_amdgcn_global_load_lds((const __attribute__((address_space(1))) unsigned int*)g,
                                   (__attribute__((address_space(3))) unsigned int*)l,
                                   16, 0, 0);
}
// 256-thread version (4 waves)
__device__ inline void stageB_chunk(const unsigned short* __restrict__ chunk,
                                    unsigned short* __restrict__ lds) {
  int w = threadIdx.x >> 6, l = threadIdx.x & 63;
  const unsigned short* s = chunk + w * 1024 + l * 8;
  unsigned short* d = lds + w * 1024;
  gload16(s, d);
  gload16(s + 512, d + 512);
}

#define WAIT_ALL  asm volatile("s_waitcnt vmcnt(0) lgkmcnt(0)" ::: "memory")
#define SCHEDBAR  __builtin_amdgcn_sched_barrier(0)
#define BAR       __builtin_amdgcn_s_barrier()

// ---------------- MFMA cores (256-thread GEMMs) ----------------

__device__ inline void mma16(const unsigned short* As, const unsigned short* Bs,
                             int wr, int wc, f32x4 acc[4][4]) {
  int l = threadIdx.x & 63;
  int lr = l & 15, lg = l >> 4;
  int qoff = ((lg ^ ((lr ^ (lr >> 2)) & 3)) << 3);
  short8 a[4], b[4];
#pragma unroll
  for (int m = 0; m < 4; m++)
    a[m] = *(const short8*)(As + (wr + m * 16 + lr) * 32 + qoff);
#pragma unroll
  for (int n = 0; n < 4; n++)
    b[n] = *(const short8*)(Bs + (wc + n * 16 + lr) * 32 + qoff);
#pragma unroll
  for (int m = 0; m < 4; m++)
#pragma unroll
    for (int n = 0; n < 4; n++)
      acc[m][n] = __builtin_amdgcn_mfma_f32_16x16x32_bf16(a[m], b[n], acc[m][n], 0, 0, 0);
}

__device__ inline void mma16_dualB(const unsigned short* As, const unsigned short* Bs1,
                                   const unsigned short* Bs2, int wr, int wc,
                                   f32x4 acc1[4][4], f32x4 acc2[4][4]) {
  int l = threadIdx.x & 63;
  int lr = l & 15, lg = l >> 4;
  int qoff = ((lg ^ ((lr ^ (lr >> 2)) & 3)) << 3);
  short8 a[4], b1[4], b2[4];
#pragma unroll
  for (int m = 0; m < 4; m++)
    a[m] = *(const short8*)(As + (wr + m * 16 + lr) * 32 + qoff);
#pragma unroll
  for (int n = 0; n < 4; n++) {
    b1[n] = *(const short8*)(Bs1 + (wc + n * 16 + lr) * 32 + qoff);
    b2[n] = *(const short8*)(Bs2 + (wc + n * 16 + lr) * 32 + qoff);
  }
#pragma unroll
  for (int m = 0; m < 4; m++)
#pragma unroll
    for (int n = 0; n < 4; n++) {
      acc1[m][n] = __builtin_amdgcn_mfma_f32_16x16x32_bf16(a[m], b1[n], acc1[m][n], 0, 0, 0);
      acc2[m][n] = __builtin_amdgcn_mfma_f32_16x16x32_bf16(a[m], b2[n], acc2[m][n], 0, 0, 0);
    }
}

__device__ inline void mma16_split_reg(const unsigned short* Ash, const unsigned short* Asl,
                                       const unsigned short* Bsh, const unsigned short* Bsl,
                                       int wr, int wc, f32x4 acc[4][4]) {
  int l = threadIdx.x & 63;
  int lr = l & 15, lg = l >> 4;
  int qoff = ((lg ^ ((lr ^ (lr >> 2)) & 3)) << 3);
  short8 ah[4], al[4], bh[4], bl[4];
#pragma unroll
  for (int m = 0; m < 4; m++) {
    ah[m] = *(const short8*)(Ash + (wr + m * 16 + lr) * 32 + qoff);
    al[m] = *(const short8*)(Asl + (wr + m * 16 + lr) * 32 + qoff);
  }
#pragma unroll
  for (int n = 0; n < 4; n++) {
    bh[n] = *(const short8*)(Bsh + (wc + n * 16 + lr) * 32 + qoff);
    bl[n] = *(const short8*)(Bsl + (wc + n * 16 + lr) * 32 + qoff);
  }
#pragma unroll
  for (int m = 0; m < 4; m++)
#pragma unroll
    for (int n = 0; n < 4; n++) {
      acc[m][n] = __builtin_amdgcn_mfma_f32_16x16x32_bf16(ah[m], bh[n], acc[m][n], 0, 0, 0);
      acc[m][n] = __builtin_amdgcn_mfma_f32_16x16x32_bf16(ah[m], bl[n], acc[m][n], 0, 0, 0);
      acc[m][n] = __builtin_amdgcn_mfma_f32_16x16x32_bf16(al[m], bh[n], acc[m][n], 0, 0, 0);
    }
}

// ---------------- pack kernels: f32 [K][N] -> pre-swizzled 8KB bf16 chunks ----------------

__global__ __launch_bounds__(256) void k_pack1(const float* __restrict__ src, long ld,
                                               long zs, int nc,
                                               unsigned short* __restrict__ dst) {
  __shared__ float tile[32][132];
  const float* Sp = src + (long)blockIdx.z * zs;
  int c = blockIdx.x, t = threadIdx.x;
  for (int i = 0; i < 4; i++) {
    int kt = blockIdx.y * 4 + i;
    long k0 = (long)kt * 32, n0 = (long)c * 128;
    {
      int k = t >> 3, nn = (t & 7) * 16;
      const float4* p = (const float4*)(Sp + (k0 + k) * ld + n0 + nn);
#pragma unroll
      for (int j = 0; j < 4; j++) *(float4*)&tile[k][nn + j * 4] = p[j];
    }
    __syncthreads();
    size_t cbase = ((size_t)(blockIdx.z * nc + c) * 64 + kt) * 4096;
#pragma unroll
    for (int uu = 0; uu < 2; uu++) {
      int u = t * 2 + uu;
      int n = u >> 2, qp = u & 3;
      int q = qp ^ ((n ^ (n >> 2)) & 3);
      unsigned short hb[8] __attribute__((aligned(16)));
#pragma unroll
      for (int j = 0; j < 8; j++) hb[j] = f2bf(tile[8 * q + j][n]);
      *(uint4*)(dst + cbase + u * 8) = *(const uint4*)hb;
    }
    __syncthreads();
  }
}

__global__ __launch_bounds__(256) void k_pack2(const float* __restrict__ src, long ld,
                                               long zs, int nc,
                                               unsigned short* __restrict__ dh,
                                               unsigned short* __restrict__ dl) {
  __shared__ float tile[32][132];
  const float* Sp = src + (long)blockIdx.z * zs;
  int c = blockIdx.x, t = threadIdx.x;
  for (int i = 0; i < 4; i++) {
    int kt = blockIdx.y * 4 + i;
    long k0 = (long)kt * 32, n0 = (long)c * 128;
    {
      int k = t >> 3, nn = (t & 7) * 16;
      const float4* p = (const float4*)(Sp + (k0 + k) * ld + n0 + nn);
#pragma unroll
      for (int j = 0; j < 4; j++) *(float4*)&tile[k][nn + j * 4] = p[j];
    }
    __syncthreads();
    size_t cbase = ((size_t)(blockIdx.z * nc + c) * 64 + kt) * 4096;
#pragma unroll
    for (int uu = 0; uu < 2; uu++) {
      int u = t * 2 + uu;
      int n = u >> 2, qp = u & 3;
      int q = qp ^ ((n ^ (n >> 2)) & 3);
      unsigned short hb[8] __attribute__((aligned(16)));
      unsigned short lb[8] __attribute__((aligned(16)));
#pragma unroll
      for (int j = 0; j < 8; j++) split2(tile[8 * q + j][n], hb[j], lb[j]);
      *(uint4*)(dh + cbase + u * 8) = *(const uint4*)hb;
      *(uint4*)(dl + cbase + u * 8) = *(const uint4*)lb;
    }
    __syncthreads();
  }
}

// pack bf16 [z][S][HD] -> chunks [z][64][4096] (8KB B-chunk image: rows=tokens, k=HD)
__global__ __launch_bounds__(256) void k_packbf(const unsigned short* __restrict__ src,
                                                unsigned short* __restrict__ dst) {
  int ttile = blockIdx.x;  // 0..15 (128-token tiles)
  int z = blockIdx.y;      // kv head
  const unsigned short* Sp = src + ((size_t)z * S_LEN + (size_t)ttile * 128) * HD;
  size_t ob = ((size_t)z * 64 + (size_t)ttile * 4) * 4096;
  int t = threadIdx.x;
#pragma unroll
  for (int kst = 0; kst < 4; kst++) {
#pragma unroll
    for (int uu = 0; uu < 2; uu++) {
      int u = t * 2 + uu;
      int n = u >> 2, qp = u & 3;
      int q = qp ^ ((n ^ (n >> 2)) & 3);
      *(uint4*)(dst + ob + (size_t)kst * 4096 + u * 8) =
          *(const uint4*)(Sp + (size_t)n * HD + kst * 32 + q * 8);
    }
  }
}

// ---------------- qkv / wo GEMMs (fp32-emulated, 2-phase pipelined) ----------------

__global__ __launch_bounds__(256) void k_qkv_s(const unsigned short* __restrict__ Ah,
                                               const unsigned short* __restrict__ Al,
                                               const unsigned short* __restrict__ BPh,
                                               const unsigned short* __restrict__ BPl,
                                               float* __restrict__ C) {
  __shared__ unsigned short Ash[2 * 4096], Asl[2 * 4096], Bsh[2 * 4096], Bsl[2 * 4096];
  int row0 = blockIdx.y * 128;
  size_t cb = (size_t)blockIdx.x * 64 * 4096;
  int w = threadIdx.x >> 6;
  int wr = (w >> 1) * 64, wc = (w & 1) * 64;
  uint4 vah[2], val[2];
  loadA2_rows(Ah, DMODEL, row0, 0, vah);
  loadA2_rows(Al, DMODEL, row0, 0, val);
  stageB_chunk(BPh + cb, Bsh);
  stageB_chunk(BPl + cb, Bsl);
  writeA2(vah, Ash);
  writeA2(val, Asl);
  WAIT_ALL;
  BAR;
  f32x4 acc[4][4] = {};
  for (int kt = 0; kt < 64; kt++) {
    int cur = (kt & 1) << 12, nxt = 4096 - cur;
    if (kt + 1 < 64) {
      loadA2_rows(Ah, DMODEL, row0, (kt + 1) * 32, vah);
      loadA2_rows(Al, DMODEL, row0, (kt + 1) * 32, val);
      stageB_chunk(BPh + cb + (size_t)(kt + 1) * 4096, Bsh + nxt);
      stageB_chunk(BPl + cb + (size_t)(kt + 1) * 4096, Bsl + nxt);
    }
    SCHEDBAR;
    mma16_split_reg(Ash + cur, Asl + cur, Bsh + cur, Bsl + cur, wr, wc, acc);
    SCHEDBAR;
    if (kt + 1 < 64) {
      writeA2(vah, Ash + nxt);
      writeA2(val, Asl + nxt);
    }
    WAIT_ALL;
    BAR;
  }
  int col0 = blockIdx.x * 128;
  int l = threadIdx.x & 63;
  int er = wr + ((l >> 4) << 2), ec = wc + (l & 15);
#pragma unroll
  for (int m = 0; m < 4; m++)
#pragma unroll
    for (int n = 0; n < 4; n++)
#pragma unroll
      for (int r = 0; r < 4; r++) {
        float v = acc[m][n][r];
        v = fminf(fmaxf(v, -8.f), 8.f);
        C[(size_t)(row0 + er + m * 16 + r) * QKV_N + col0 + ec + n * 16] = v;
      }
}

__global__ __launch_bounds__(256) void k_wo_s(const unsigned short* __restrict__ Ah,
                                              const unsigned short* __restrict__ Al,
                                              const unsigned short* __restrict__ BPh,
                                              const unsigned short* __restrict__ BPl,
                                              const float* __restrict__ resid,
                                              float* __restrict__ x1) {
  __shared__ unsigned short Ash[2 * 4096], Asl[2 * 4096], Bsh[2 * 4096], Bsl[2 * 4096];
  int row0 = blockIdx.y * 128;
  size_t cb = (size_t)blockIdx.x * 64 * 4096;
  int w = threadIdx.x >> 6;
  int wr = (w >> 1) * 64, wc = (w & 1) * 64;
  uint4 vah[2], val[2];
  loadA2_rows(Ah, DMODEL, row0, 0, vah);
  loadA2_rows(Al, DMODEL, row0, 0, val);
  stageB_chunk(BPh + cb, Bsh);
  stageB_chunk(BPl + cb, Bsl);
  writeA2(vah, Ash);
  writeA2(val, Asl);
  WAIT_ALL;
  BAR;
  f32x4 acc[4][4] = {};
  for (int kt = 0; kt < 64; kt++) {
    int cur = (kt & 1) << 12, nxt = 4096 - cur;
    if (kt + 1 < 64) {
      loadA2_rows(Ah, DMODEL, row0, (kt + 1) * 32, vah);
      loadA2_rows(Al, DMODEL, row0, (kt + 1) * 32, val);
      stageB_chunk(BPh + cb + (size_t)(kt + 1) * 4096, Bsh + nxt);
      stageB_chunk(BPl + cb + (size_t)(kt + 1) * 4096, Bsl + nxt);
    }
    SCHEDBAR;
    mma16_split_reg(Ash + cur, Asl + cur, Bsh + cur, Bsl + cur, wr, wc, acc);
    SCHEDBAR;
    if (kt + 1 < 64) {
      writeA2(vah, Ash + nxt);
      writeA2(val, Asl + nxt);
    }
    WAIT_ALL;
    BAR;
  }
  int col0 = blockIdx.x * 128;
  int l = threadIdx.x & 63;
  int er = wr + ((l >> 4) << 2), ec = wc + (l & 15);
#pragma unroll
  for (int m = 0; m < 4; m++)
#pragma unroll
    for (int n = 0; n < 4; n++)
#pragma unroll
      for (int r = 0; r < 4; r++) {
        size_t idx = (size_t)(row0 + er + m * 16 + r) * DMODEL + col0 + ec + n * 16;
        x1[idx] = resid[idx] + acc[m][n][r];
      }
}

// ---------------- flash attention (fp32-emulated, online softmax) ----------------
// grid (16 heads, 32 row-tiles of 64). 128 threads = 2 waves, each owns 32 rows.

__global__ __launch_bounds__(128) void k_flash(const unsigned short* __restrict__ qh,
                                               const unsigned short* __restrict__ ql,
                                               const unsigned short* __restrict__ kPh,
                                               const unsigned short* __restrict__ kPl,
                                               const unsigned short* __restrict__ vPh,
                                               const unsigned short* __restrict__ vPl,
                                               unsigned short* __restrict__ ath,
                                               unsigned short* __restrict__ atl) {
  int h = blockIdx.x;
  int rt = blockIdx.y;
  int kv = h >> 2;
  int row0 = rt * 64;
  int ntiles = (rt >> 1) + 1;
  __shared__ unsigned short KV[2][2][4096];  // [buf][hi/lo][8KB chunk]
  __shared__ float Pds[2][32 * 128];         // per-wave P scratch (f32)
  int t = threadIdx.x;
  int w = t >> 6, l = t & 63;
  int lr = l & 15, lg = l >> 4;
  int qoff = ((lg ^ ((lr ^ (lr >> 2)) & 3)) << 3);
  int wrow0 = row0 + w * 32;
  const unsigned short* Qbh = qh + (size_t)h * S_LEN * HD;
  const unsigned short* Qbl = ql + (size_t)h * S_LEN * HD;
  const unsigned short* Kch = kPh + (size_t)kv * 64 * 4096;
  const unsigned short* Kcl = kPl + (size_t)kv * 64 * 4096;
  const unsigned short* Vch = vPh + (size_t)kv * 64 * 4096;
  const unsigned short* Vcl = vPl + (size_t)kv * 64 * 4096;
  // Q fragments in registers (hi/lo), m in {0,1}, kst in 0..3
  short8 qfh[2][4], qfl[2][4];
#pragma unroll
  for (int m = 0; m < 2; m++)
#pragma unroll
    for (int kst = 0; kst < 4; kst++) {
      size_t o = (size_t)(wrow0 + m * 16 + lr) * HD + kst * 32 + lg * 8;
      qfh[m][kst] = *(const short8*)(Qbh + o);
      qfl[m][kst] = *(const short8*)(Qbl + o);
    }
  float mrun[2][4], lrun[2][4];
  f32x4 Oc[2][8];
#pragma unroll
  for (int m = 0; m < 2; m++)
#pragma unroll
    for (int r = 0; r < 4; r++) { mrun[m][r] = -3.4e38f; lrun[m][r] = 0.f; }
#pragma unroll
  for (int m = 0; m < 2; m++)
#pragma unroll
    for (int n = 0; n < 8; n++)
#pragma unroll
      for (int r = 0; r < 4; r++) Oc[m][n][r] = 0.f;

  auto STAGE = [&](int tile, int ph, int b) {
    const unsigned short* base;
    if (ph < 4)
      base = (w ? Kcl : Kch) + ((size_t)tile * 4 + ph) * 4096;
    else
      base = (w ? Vcl : Vch) + ((size_t)tile * 4 + (ph - 4)) * 4096;
    const unsigned short* s = base + l * 8;
    unsigned short* d = &KV[b][w][0];
#pragma unroll
    for (int i = 0; i < 8; i++) gload16(s + i * 512, d + i * 512);
  };

  f32x4 Sa[2][8];
  int buf = 0;
  STAGE(0, 0, 0);
  WAIT_ALL;
  BAR;
  const float scale = 0.08838834764831845f;  // 1/sqrt(128)
  for (int kt = 0; kt < ntiles; kt++) {
#pragma unroll
    for (int m = 0; m < 2; m++)
#pragma unroll
      for (int n = 0; n < 8; n++)
#pragma unroll
        for (int r = 0; r < 4; r++) Sa[m][n][r] = 0.f;
    for (int ph = 0; ph < 8; ph++) {
      {
        int nph = ph + 1, nkt = kt;
        if (nph == 8) { nph = 0; nkt = kt + 1; }
        if (nkt < ntiles) STAGE(nkt, nph, buf ^ 1);
      }
      SCHEDBAR;
      if (ph < 4) {
        const unsigned short* Bh = &KV[buf][0][0];
        const unsigned short* Bl = &KV[buf][1][0];
        short8 bh[8], bl[8];
#pragma unroll
        for (int n = 0; n < 8; n++) {
          bh[n] = *(const short8*)(Bh + (n * 16 + lr) * 32 + qoff);
          bl[n] = *(const short8*)(Bl + (n * 16 + lr) * 32 + qoff);
        }
#pragma unroll
        for (int m = 0; m < 2; m++)
#pragma unroll
          for (int n = 0; n < 8; n++) {
            Sa[m][n] = __builtin_amdgcn_mfma_f32_16x16x32_bf16(qfh[m][ph], bh[n], Sa[m][n], 0, 0, 0);
            Sa[m][n] = __builtin_amdgcn_mfma_f32_16x16x32_bf16(qfh[m][ph], bl[n], Sa[m][n], 0, 0, 0);
            Sa[m][n] = __builtin_amdgcn_mfma_f32_16x16x32_bf16(qfl[m][ph], bh[n], Sa[m][n], 0, 0, 0);
          }
        if (ph == 3) {
          // online softmax update + P write (all intra-wave)
#pragma unroll
          for (int m = 0; m < 2; m++)
#pragma unroll
            for (int r = 0; r < 4; r++) {
              int row = wrow0 + m * 16 + lg * 4 + r;
              float mx = mrun[m][r];
#pragma unroll
              for (int n = 0; n < 8; n++) {
                float v = Sa[m][n][r] * scale;
                int col = kt * 128 + n * 16 + lr;
                v = (col <= row) ? v : -3.4e38f;
                Sa[m][n][r] = v;
                mx = fmaxf(mx, v);
              }
              mx = fmaxf(mx, __shfl_xor(mx, 1));
              mx = fmaxf(mx, __shfl_xor(mx, 2));
              mx = fmaxf(mx, __shfl_xor(mx, 4));
              mx = fmaxf(mx, __shfl_xor(mx, 8));
              float al_ = expf(mrun[m][r] - mx);
              float sum = 0.f;
#pragma unroll
              for (int n = 0; n < 8; n++) {
                float v = Sa[m][n][r];
                float e = (v > -1.0e37f) ? expf(v - mx) : 0.f;
                Sa[m][n][r] = e;
                sum += e;
              }
              sum += __shfl_xor(sum, 1);
              sum += __shfl_xor(sum, 2);
              sum += __shfl_xor(sum, 4);
              sum += __shfl_xor(sum, 8);
              lrun[m][r] = lrun[m][r] * al_ + sum;
              mrun[m][r] = mx;
#pragma unroll
              for (int n = 0; n < 8; n++) Oc[m][n][r] *= al_;
            }
          // write P (unnormalized, f32) to per-wave LDS
#pragma unroll
          for (int m = 0; m < 2; m++)
#pragma unroll
            for (int n = 0; n < 8; n++)
#pragma unroll
              for (int r = 0; r < 4; r++)
                Pds[w][(m * 16 + lg * 4 + r) * 128 + n * 16 + lr] = Sa[m][n][r];
        }
      } else {
        int kst2 = ph - 4;
        const unsigned short* Bh = &KV[buf][0][0];
        const unsigned short* Bl = &KV[buf][1][0];
        short8 bh[8], bl[8];
#pragma unroll
        for (int n = 0; n < 8; n++) {
          bh[n] = *(const short8*)(Bh + (n * 16 + lr) * 32 + qoff);
          bl[n] = *(const short8*)(Bl + (n * 16 + lr) * 32 + qoff);
        }
#pragma unroll
        for (int m = 0; m < 2; m++) {
          const float* pp = &Pds[w][(m * 16 + lr) * 128 + kst2 * 32 + lg * 8];
          unsigned short ahb[8] __attribute__((aligned(16)));
          unsigned short alb[8] __attribute__((aligned(16)));
#pragma unroll
          for (int j = 0; j < 8; j++) split2(pp[j], ahb[j], alb[j]);
          short8 ah = *(const short8*)ahb;
          short8 al_ = *(const short8*)alb;
#pragma unroll
          for (int n = 0; n < 8; n++) {
            Oc[m][n] = __builtin_amdgcn_mfma_f32_16x16x32_bf16(ah, bh[n], Oc[m][n], 0, 0, 0);
            Oc[m][n] = __builtin_amdgcn_mfma_f32_16x16x32_bf16(ah, bl[n], Oc[m][n], 0, 0, 0);
            Oc[m][n] = __builtin_amdgcn_mfma_f32_16x16x32_bf16(al_, bh[n], Oc[m][n], 0, 0, 0);
          }
        }
      }
      SCHEDBAR;
      WAIT_ALL;
      BAR;
      buf ^= 1;
    }
  }
  // epilogue: O / l -> split bf16 -> global
#pragma unroll
  for (int m = 0; m < 2; m++)
#pragma unroll
    for (int r = 0; r < 4; r++) {
      size_t row = wrow0 + m * 16 + lg * 4 + r;
      float lv = lrun[m][r];
#pragma unroll
      for (int n = 0; n < 8; n++) {
        unsigned short hh, ll;
        split2(Oc[m][n][r] / lv, hh, ll);
        size_t o = row * DMODEL + (size_t)h * HD + n * 16 + lr;
        ath[o] = hh;
        atl[o] = ll;
      }
    }
}

// ---------------- MoE GEMMs: fused up-proj + down-proj, 2-phase pipelined ----------------

// g = silu(h2 @ w1[e]) * (h2 @ v1[e])
__global__ __launch_bounds__(256) void k_moe1f(const unsigned short* __restrict__ h2b,
                                               const unsigned short* __restrict__ wPa,
                                               const unsigned short* __restrict__ wPb,
                                               const int* __restrict__ off,
                                               const int* __restrict__ ptok,
                                               const int* __restrict__ meta,
                                               unsigned short* __restrict__ g) {
  int ty = blockIdx.y;
  if (ty >= meta[25]) return;
  int tt = meta[26 + ty];
  int e = tt & 7, m0 = tt >> 3;
  int nvalid = min(128, meta[e] - m0);
  const int* toks = ptok + off[e] + m0;
  const unsigned short* B1 = wPa + (size_t)(e * 16 + blockIdx.x) * 64 * 4096;
  const unsigned short* B2 = wPb + (size_t)(e * 16 + blockIdx.x) * 64 * 4096;
  __shared__ unsigned short As[2 * 4096], Bs1[2 * 4096], Bs2[2 * 4096];
  int w = threadIdx.x >> 6;
  int wr = (w >> 1) * 64, wc = (w & 1) * 64;
  uint4 va[2];
  loadA2_g(h2b, DMODEL, toks, nvalid, 0, va);
  stageB_chunk(B1, Bs1);
  stageB_chunk(B2, Bs2);
  writeA2(va, As);
  WAIT_ALL;
  BAR;
  f32x4 acc1[4][4] = {}, acc2[4][4] = {};
  for (int kt = 0; kt < 64; kt++) {
    int cur = (kt & 1) << 12, nxt = 4096 - cur;
    if (kt + 1 < 64) {
      loadA2_g(h2b, DMODEL, toks, nvalid, (kt + 1) * 32, va);
      stageB_chunk(B1 + (size_t)(kt + 1) * 4096, Bs1 + nxt);
      stageB_chunk(B2 + (size_t)(kt + 1) * 4096, Bs2 + nxt);
    }
    SCHEDBAR;
    mma16_dualB(As + cur, Bs1 + cur, Bs2 + cur, wr, wc, acc1, acc2);
    SCHEDBAR;
    if (kt + 1 < 64) writeA2(va, As + nxt);
    WAIT_ALL;
    BAR;
  }
  int col0 = blockIdx.x * 128;
  int l = threadIdx.x & 63;
  int er = wr + ((l >> 4) << 2), ec = wc + (l & 15);
  size_t gbase = (size_t)off[e] + m0;
#pragma unroll
  for (int m = 0; m < 4; m++)
#pragma unroll
    for (int n = 0; n < 4; n++)
#pragma unroll
      for (int r = 0; r < 4; r++) {
        int rl = er + m * 16 + r;
        if (rl < nvalid) {
          float a = acc1[m][n][r];
          float s = a / (1.f + expf(-a));
          g[(gbase + rl) * FF + col0 + ec + n * 16] = f2bf(s * acc2[m][n][r]);
        }
      }
}

__global__ __launch_bounds__(256) void k_moe2(const unsigned short* __restrict__ g,
                                              const unsigned short* __restrict__ wP,
                                              const int* __restrict__ off,
                                              const int* __restrict__ ptok,
                                              const float* __restrict__ pw,
                                              const int* __restrict__ meta,
                                              float* __restrict__ y) {
  int ty = blockIdx.y;
  if (ty >= meta[25]) return;
  int tt = meta[26 + ty];
  int e = tt & 7, m0 = tt >> 3;
  int nvalid = min(128, meta[e] - m0);
  long pbase = (long)off[e] + m0;
  const unsigned short* Bb = wP + (size_t)(e * 16 + blockIdx.x) * 64 * 4096;
  __shared__ unsigned short As[2 * 4096], Bs[2 * 4096];
  int w = threadIdx.x >> 6;
  int wr = (w >> 1) * 64, wc = (w & 1) * 64;
  uint4 va[2];
  loadA2_rows(g, FF, pbase, 0, va);
  stageB_chunk(Bb, Bs);
  writeA2(va, As);
  WAIT_ALL;
  BAR;
  f32x4 acc[4][4] = {};
  for (int kt = 0; kt < 64; kt++) {
    int cur = (kt & 1) << 12, nxt = 4096 - cur;
    if (kt + 1 < 64) {
      loadA2_rows(g, FF, pbase, (kt + 1) * 32, va);
      stageB_chunk(Bb + (size_t)(kt + 1) * 4096, Bs + nxt);
    }
    SCHEDBAR;
    mma16(As + cur, Bs + cur, wr, wc, acc);
    SCHEDBAR;
    if (kt + 1 < 64) writeA2(va, As + nxt);
    WAIT_ALL;
    BAR;
  }
  int col0 = blockIdx.x * 128;
  int l = threadIdx.x & 63;
  int er = wr + ((l >> 4) << 2), ec = wc + (l & 15);
#pragma unroll
  for (int m = 0; m < 4; m++)
#pragma unroll
    for (int n = 0; n < 4; n++)
#pragma unroll
      for (int r = 0; r < 4; r++) {
        int rl = er + m * 16 + r;
        if (rl < nvalid) {
          long p = pbase + rl;
          int tk = ptok[p];
          atomicAdd(&y[(size_t)tk * DMODEL + col0 + ec + n * 16], acc[m][n][r] * pw[p]);
        }
      }
}

// ---------------- small kernels ----------------

__global__ __launch_bounds__(256) void k_ln(const float* __restrict__ x,
                                            const float* __restrict__ w,
                                            unsigned short* __restrict__ obh,
                                            unsigned short* __restrict__ obl,
                                            float* __restrict__ of) {
  int row = blockIdx.x;
  const float* xr = x + (size_t)row * DMODEL;
  float s = 0.f, ss = 0.f;
  for (int c = threadIdx.x; c < DMODEL; c += 256) {
    float v = xr[c];
    s += v; ss += v * v;
  }
#pragma unroll
  for (int o = 32; o; o >>= 1) { s += __shfl_down(s, o); ss += __shfl_down(ss, o); }
  __shared__ float rs[4], rss[4], mu_s, inv_s;
  int wid = threadIdx.x >> 6;
  if ((threadIdx.x & 63) == 0) { rs[wid] = s; rss[wid] = ss; }
  __syncthreads();
  if (threadIdx.x == 0) {
    float S1 = rs[0] + rs[1] + rs[2] + rs[3];
    float S2 = rss[0] + rss[1] + rss[2] + rss[3];
    float mu = S1 / DMODEL;
    mu_s = mu;
    inv_s = rsqrtf(S2 / DMODEL - mu * mu + 1e-5f);
  }
  __syncthreads();
  float mu = mu_s, inv = inv_s;
  for (int c = threadIdx.x; c < DMODEL; c += 256) {
    float v = (xr[c] - mu) * inv * w[c];
    unsigned short hh, ll;
    split2(v, hh, ll);
    obh[(size_t)row * DMODEL + c] = hh;
    if (obl) obl[(size_t)row * DMODEL + c] = ll;
    if (of) of[(size_t)row * DMODEL + c] = v;
  }
}

__global__ void k_rope2(const float* __restrict__ qkv, unsigned short* __restrict__ qh,
                        unsigned short* __restrict__ ql, unsigned short* __restrict__ kh,
                        unsigned short* __restrict__ kl) {
  int t = blockIdx.x;
  int d = threadIdx.x;  // 0..63
  float pf = (float)pow(500000.0, (double)d * (1.0 / 64.0));
  float invf = 1.0f / pf;
  float ang = (float)t * invf;
  float cs = (float)cos((double)ang);
  float sn = (float)sin((double)ang);
  const float* row = qkv + (size_t)t * QKV_N;
  unsigned short hh, ll;
#pragma unroll
  for (int hq = 0; hq < NH; hq++) {
    float a = row[hq * HD + d], b = row[hq * HD + d + 64];
    size_t base = ((size_t)hq * S_LEN + t) * HD;
    split2(a * cs - b * sn, hh, ll); qh[base + d] = hh; ql[base + d] = ll;
    split2(b * cs + a * sn, hh, ll); qh[base + d + 64] = hh; ql[base + d + 64] = ll;
  }
#pragma unroll
  for (int kv = 0; kv < NKV; kv++) {
    float a = row[NH * HD + kv * HD + d], b = row[NH * HD + kv * HD + d + 64];
    size_t base = ((size_t)kv * S_LEN + t) * HD;
    split2(a * cs - b * sn, hh, ll); kh[base + d] = hh; kl[base + d] = ll;
    split2(b * cs + a * sn, hh, ll); kh[base + d + 64] = hh; kl[base + d + 64] = ll;
  }
}

__global__ __launch_bounds__(256) void k_router(const float* __restrict__ h2,
                                                const float* __restrict__ rw,
                                                int* __restrict__ topi,
                                                float* __restrict__ topw,
                                                int* __restrict__ cnt) {
  int t = blockIdx.x;
  __shared__ float hs[DMODEL];
  __shared__ float lg[NE];
  for (int c = threadIdx.x; c < DMODEL; c += 256) hs[c] = h2[(size_t)t * DMODEL + c];
  __syncthreads();
  int grp = threadIdx.x >> 5;
  int ln = threadIdx.x & 31;
  float p = 0.f;
  for (int c = ln; c < DMODEL; c += 32) p += hs[c] * rw[(size_t)grp * DMODEL + c];
#pragma unroll
  for (int o = 16; o; o >>= 1) p += __shfl_down(p, o, 32);
  if (ln == 0) lg[grp] = p;
  __syncthreads();
  if (threadIdx.x == 0) {
    float l0 = -3.4e38f; int i0 = 0;
    for (int e = 0; e < NE; e++)
      if (lg[e] > l0) { l0 = lg[e]; i0 = e; }
    float l1 = -3.4e38f; int i1 = 0;
    for (int e = 0; e < NE; e++)
      if (e != i0 && lg[e] > l1) { l1 = lg[e]; i1 = e; }
    float z = expf(l1 - l0);
    topi[t * 2] = i0; topi[t * 2 + 1] = i1;
    topw[t * 2] = 1.f / (1.f + z); topw[t * 2 + 1] = z / (1.f + z);
    atomicAdd(&cnt[i0], 1);
    atomicAdd(&cnt[i1], 1);
  }
}

__global__ void k_scan(int* __restrict__ meta) {
  if (threadIdx.x == 0 && blockIdx.x == 0) {
    int o = 0, nt = 0;
    for (int e = 0; e < NE; e++) {
      meta[16 + e] = o;
      for (int m0 = 0; m0 < meta[e]; m0 += 128) meta[26 + nt++] = (m0 << 3) | e;
      o += meta[e];
    }
    meta[24] = o;
    meta[25] = nt;
  }
}

__global__ void k_fill(const int* __restrict__ topi, const float* __restrict__ topw,
                       int* __restrict__ meta, int* __restrict__ ptok,
                       float* __restrict__ pw) {
  int t = blockIdx.x * blockDim.x + threadIdx.x;
  if (t >= S_LEN) return;
#pragma unroll
  for (int j = 0; j < 2; j++) {
    int e = topi[t * 2 + j];
    int p = atomicAdd(&meta[8 + e], 1);
    ptok[meta[16 + e] + p] = t;
    pw[meta[16 + e] + p] = topw[t * 2 + j];
  }
}

// out += y (in place; out holds x1)
__global__ void k_final(float* __restrict__ out, const float* __restrict__ y) {
  int i = blockIdx.x * blockDim.x + threadIdx.x;
  float4 a = ((const float4*)out)[i];
  float4 b = ((const float4*)y)[i];
  ((float4*)out)[i] = make_float4(a.x + b.x, a.y + b.y, a.z + b.z, a.w + b.w);
}

// ---------------- launch ----------------

extern "C" void kernel_launch(void* const* d_in, const int* in_sizes, int n_in,
                              void* d_out, int out_size, void* d_ws, size_t ws_size,
                              hipStream_t stream) {
  (void)in_sizes; (void)n_in; (void)out_size; (void)ws_size;
  const float* x = (const float*)d_in[0];
  const float* ln1w = (const float*)d_in[2];
  const float* ln2w = (const float*)d_in[3];
  const float* wqkv = (const float*)d_in[4];
  const float* wo = (const float*)d_in[5];
  const float* rw = (const float*)d_in[6];
  const float* w1 = (const float*)d_in[7];
  const float* v1 = (const float*)d_in[8];
  const float* w2 = (const float*)d_in[9];
  float* out = (float*)d_out;  // holds x1 after k_wo_s

  char* wsb = (char*)d_ws;
  const size_t MiB = 1u << 20;
  // ---- attention phase ----
  unsigned short* h1h = (unsigned short*)(wsb + 0 * MiB);      // 8
  unsigned short* h1l = (unsigned short*)(wsb + 8 * MiB);      // 8
  float* qkvb = (float*)(wsb + 16 * MiB);                      // 24
  unsigned short* qh = (unsigned short*)(wsb + 40 * MiB);      // 8
  unsigned short* ql = (unsigned short*)(wsb + 48 * MiB);      // 8
  unsigned short* kh = (unsigned short*)(wsb + 56 * MiB);      // 2
  unsigned short* kl = (unsigned short*)(wsb + 58 * MiB);      // 2
  unsigned short* vPh = (unsigned short*)(wsb + 60 * MiB);     // 2
  unsigned short* vPl = (unsigned short*)(wsb + 62 * MiB);     // 2
  unsigned short* kPh = (unsigned short*)(wsb + 64 * MiB);     // 2
  unsigned short* kPl = (unsigned short*)(wsb + 66 * MiB);     // 2
  unsigned short* ath = (unsigned short*)(wsb + 68 * MiB);     // 8
  unsigned short* atl = (unsigned short*)(wsb + 76 * MiB);     // 8
  unsigned short* wqkvPh = (unsigned short*)(wsb + 84 * MiB);  // 12
  unsigned short* wqkvPl = (unsigned short*)(wsb + 96 * MiB);  // 12
  unsigned short* woPh = (unsigned short*)(wsb + 108 * MiB);   // 8
  unsigned short* woPl = (unsigned short*)(wsb + 116 * MiB);   // 8
  // ---- MoE phase (over dead attention buffers) ----
  float* h2f = (float*)(wsb + 0 * MiB);                        // 16 (over h1)
  unsigned short* h2b = (unsigned short*)(wsb + 16 * MiB);     // 8 (over qkvb)
  unsigned short* g = (unsigned short*)(wsb + 24 * MiB);       // 16 (over qkvb)
  float* y = (float*)(wsb + 40 * MiB);                         // 16 (over qh/ql)
  unsigned short* wPa = (unsigned short*)(wsb + 56 * MiB);     // 64 (over k/vP/kP/at/wqkvP)
  unsigned short* wPb = (unsigned short*)(wsb + 120 * MiB);    // 64
  char* small = wsb + 184 * MiB;
  int* topi = (int*)small;
  float* topw = (float*)(small + 16384);
  int* ptok = (int*)(small + 32768);
  float* pw = (float*)(small + 49152);
  int* meta = (int*)(small + 65536);  // 128 ints

  // ---- pack attention weights ----
  k_pack2<<<dim3(QKV_N / 128, 16, 1), 256, 0, stream>>>(wqkv, QKV_N, 0, QKV_N / 128,
                                                        wqkvPh, wqkvPl);
  k_pack2<<<dim3(DMODEL / 128, 16, 1), 256, 0, stream>>>(wo, DMODEL, 0, DMODEL / 128,
                                                         woPh, woPl);

  // ---- attention sublayer (fp32-emulated) ----
  k_ln<<<S_LEN, 256, 0, stream>>>(x, ln1w, h1h, h1l, (float*)nullptr);
  k_qkv_s<<<dim3(QKV_N / 128, S_LEN / 128), 256, 0, stream>>>(h1h, h1l, wqkvPh, wqkvPl, qkvb);
  k_rope2<<<S_LEN, 64, 0, stream>>>(qkvb, qh, ql, kh, kl);
  k_pack2<<<dim3(1, 16, NKV), 256, 0, stream>>>(qkvb + (NH + NKV) * HD, QKV_N, HD, 1,
                                                vPh, vPl);
  k_packbf<<<dim3(16, NKV), 256, 0, stream>>>(kh, kPh);
  k_packbf<<<dim3(16, NKV), 256, 0, stream>>>(kl, kPl);
  k_flash<<<dim3(NH, S_LEN / 64), 128, 0, stream>>>(qh, ql, kPh, kPl, vPh, vPl, ath, atl);
  k_wo_s<<<dim3(16, 16), 256, 0, stream>>>(ath, atl, woPh, woPl, x, out);

  // ---- MoE sublayer ----
  k_ln<<<S_LEN, 256, 0, stream>>>(out, ln2w, h2b, (unsigned short*)nullptr, h2f);
  hipMemsetAsync(y, 0, (size_t)S_LEN * DMODEL * 4, stream);
  hipMemsetAsync(meta, 0, 512, stream);
  k_router<<<S_LEN, 256, 0, stream>>>(h2f, rw, topi, topw, meta);
  k_scan<<<1, 64, 0, stream>>>(meta);
  k_fill<<<8, 256, 0, stream>>>(topi, topw, meta, ptok, pw);
  k_pack1<<<dim3(16, 16, NE), 256, 0, stream>>>(w1, FF, (long)DMODEL * FF, 16, wPa);
  k_pack1<<<dim3(16, 16, NE), 256, 0, stream>>>(v1, FF, (long)DMODEL * FF, 16, wPb);
  k_moe1f<<<dim3(16, 40), 256, 0, stream>>>(h2b, wPa, wPb, meta + 16, ptok, meta, g);
  k_pack1<<<dim3(16, 16, NE), 256, 0, stream>>>(w2, DMODEL, (long)FF * DMODEL, 16, wPa);
  k_moe2<<<dim3(16, 40), 256, 0, stream>>>(g, wPa, meta + 16, ptok, pw, meta, y);
  k_final<<<(S_LEN * DMODEL / 4) / 256, 256, 0, stream>>>(out, y);
}

// Round 8
// 971.830 us; speedup vs baseline: 1.8164x; 1.8164x over previous
//
#include <hip/hip_runtime.h>

#define S_LEN 2048
#define DMODEL 2048
#define NH 16
#define NKV 4
#define HD 128
#define NE 8
#define FF 2048
#define QKV_N 3072   // (H + 2*KV) * HD

typedef __attribute__((ext_vector_type(8))) short short8;
typedef __attribute__((ext_vector_type(4))) float f32x4;

__device__ inline unsigned short f2bf(float f) {
  unsigned int u = __builtin_bit_cast(unsigned int, f);
  u += 0x7fffu + ((u >> 16) & 1u);
  return (unsigned short)(u >> 16);
}
__device__ inline float bf2f(unsigned short h) {
  unsigned int u = ((unsigned int)h) << 16;
  return __builtin_bit_cast(float, u);
}
__device__ inline void split2(float v, unsigned short& h, unsigned short& l) {
  h = f2bf(v);
  l = f2bf(v - bf2f(h));
}

// ======== LDS tile: [128 rows][32 k] bf16, XOR-quad swizzle (verified r3-r7) ========

__device__ inline void stage_rows(const unsigned short* __restrict__ src, int ld,
                                  long row0, int k0, unsigned short* dst) {
  int t = threadIdx.x;
  int r = t >> 2, q = t & 3;
  int s = (r ^ (r >> 2)) & 3;
  uint4 v0 = *(const uint4*)(src + (size_t)(row0 + r) * ld + k0 + q * 8);
  uint4 v1 = *(const uint4*)(src + (size_t)(row0 + r + 64) * ld + k0 + q * 8);
  *(uint4*)(dst + r * 32 + ((q ^ s) << 3)) = v0;
  *(uint4*)(dst + (r + 64) * 32 + ((q ^ s) << 3)) = v1;
}

__device__ inline void loadA2_rows(const unsigned short* __restrict__ src, int ld,
                                   long row0, int k0, uint4 va[2]) {
  int t = threadIdx.x;
  int r = t >> 2, q = t & 3;
  va[0] = *(const uint4*)(src + (size_t)(row0 + r) * ld + k0 + q * 8);
  va[1] = *(const uint4*)(src + (size_t)(row0 + r + 64) * ld + k0 + q * 8);
}
__device__ inline void loadA2_g(const unsigned short* __restrict__ src, int ld,
                                const int* __restrict__ toks, int nvalid, int k0,
                                uint4 va[2]) {
  int t = threadIdx.x;
  int r = t >> 2, q = t & 3;
#pragma unroll
  for (int rr = 0; rr < 2; rr++) {
    int row = r + rr * 64;
    uint4 v = make_uint4(0, 0, 0, 0);
    if (row < nvalid) v = *(const uint4*)(src + (size_t)toks[row] * ld + k0 + q * 8);
    va[rr] = v;
  }
}
__device__ inline void writeA2(const uint4 va[2], unsigned short* dst) {
  int t = threadIdx.x;
  int r = t >> 2, q = t & 3;
  int s = (r ^ (r >> 2)) & 3;
  *(uint4*)(dst + r * 32 + ((q ^ s) << 3)) = va[0];
  *(uint4*)(dst + (r + 64) * 32 + ((q ^ s) << 3)) = va[1];
}

// ---- async chunk staging: 8 KB pre-swizzled chunk -> LDS, verbatim ----
__device__ inline void gload16(const void* g, void* l) {
  __builtin_amdgcn_global_load_lds((const __attribute__((address_space(1))) unsigned int*)g,
                                   (__attribute__((address_space(3))) unsigned int*)l,
                                   16, 0, 0);
}
__device__ inline void stageB_chunk(const unsigned short* __restrict__ chunk,
                                    unsigned short* __restrict__ lds) {
  int w = threadIdx.x >> 6, l = threadIdx.x & 63;
  const unsigned short* s = chunk + w * 1024 + l * 8;
  unsigned short* d = lds + w * 1024;
  gload16(s, d);
  gload16(s + 512, d + 512);
}

#define WAIT_ALL  asm volatile("s_waitcnt vmcnt(0) lgkmcnt(0)" ::: "memory")
#define WAIT_LDS  asm volatile("s_waitcnt lgkmcnt(0)" ::: "memory")
#define SCHEDBAR  __builtin_amdgcn_sched_barrier(0)
#define BAR       __builtin_amdgcn_s_barrier()

// ---------------- MFMA cores (256-thread GEMMs) ----------------

__device__ inline void mma16(const unsigned short* As, const unsigned short* Bs,
                             int wr, int wc, f32x4 acc[4][4]) {
  int l = threadIdx.x & 63;
  int lr = l & 15, lg = l >> 4;
  int qoff = ((lg ^ ((lr ^ (lr >> 2)) & 3)) << 3);
  short8 a[4], b[4];
#pragma unroll
  for (int m = 0; m < 4; m++)
    a[m] = *(const short8*)(As + (wr + m * 16 + lr) * 32 + qoff);
#pragma unroll
  for (int n = 0; n < 4; n++)
    b[n] = *(const short8*)(Bs + (wc + n * 16 + lr) * 32 + qoff);
#pragma unroll
  for (int m = 0; m < 4; m++)
#pragma unroll
    for (int n = 0; n < 4; n++)
      acc[m][n] = __builtin_amdgcn_mfma_f32_16x16x32_bf16(a[m], b[n], acc[m][n], 0, 0, 0);
}

__device__ inline void mma16_dualB(const unsigned short* As, const unsigned short* Bs1,
                                   const unsigned short* Bs2, int wr, int wc,
                                   f32x4 acc1[4][4], f32x4 acc2[4][4]) {
  int l = threadIdx.x & 63;
  int lr = l & 15, lg = l >> 4;
  int qoff = ((lg ^ ((lr ^ (lr >> 2)) & 3)) << 3);
  short8 a[4], b1[4], b2[4];
#pragma unroll
  for (int m = 0; m < 4; m++)
    a[m] = *(const short8*)(As + (wr + m * 16 + lr) * 32 + qoff);
#pragma unroll
  for (int n = 0; n < 4; n++) {
    b1[n] = *(const short8*)(Bs1 + (wc + n * 16 + lr) * 32 + qoff);
    b2[n] = *(const short8*)(Bs2 + (wc + n * 16 + lr) * 32 + qoff);
  }
#pragma unroll
  for (int m = 0; m < 4; m++)
#pragma unroll
    for (int n = 0; n < 4; n++) {
      acc1[m][n] = __builtin_amdgcn_mfma_f32_16x16x32_bf16(a[m], b1[n], acc1[m][n], 0, 0, 0);
      acc2[m][n] = __builtin_amdgcn_mfma_f32_16x16x32_bf16(a[m], b2[n], acc2[m][n], 0, 0, 0);
    }
}

__device__ inline void mma16_split_reg(const unsigned short* Ash, const unsigned short* Asl,
                                       const unsigned short* Bsh, const unsigned short* Bsl,
                                       int wr, int wc, f32x4 acc[4][4]) {
  int l = threadIdx.x & 63;
  int lr = l & 15, lg = l >> 4;
  int qoff = ((lg ^ ((lr ^ (lr >> 2)) & 3)) << 3);
  short8 ah[4], al[4], bh[4], bl[4];
#pragma unroll
  for (int m = 0; m < 4; m++) {
    ah[m] = *(const short8*)(Ash + (wr + m * 16 + lr) * 32 + qoff);
    al[m] = *(const short8*)(Asl + (wr + m * 16 + lr) * 32 + qoff);
  }
#pragma unroll
  for (int n = 0; n < 4; n++) {
    bh[n] = *(const short8*)(Bsh + (wc + n * 16 + lr) * 32 + qoff);
    bl[n] = *(const short8*)(Bsl + (wc + n * 16 + lr) * 32 + qoff);
  }
#pragma unroll
  for (int m = 0; m < 4; m++)
#pragma unroll
    for (int n = 0; n < 4; n++) {
      acc[m][n] = __builtin_amdgcn_mfma_f32_16x16x32_bf16(ah[m], bh[n], acc[m][n], 0, 0, 0);
      acc[m][n] = __builtin_amdgcn_mfma_f32_16x16x32_bf16(ah[m], bl[n], acc[m][n], 0, 0, 0);
      acc[m][n] = __builtin_amdgcn_mfma_f32_16x16x32_bf16(al[m], bh[n], acc[m][n], 0, 0, 0);
    }
}

// ---------------- pack kernels: f32 [K][N] -> pre-swizzled 8KB bf16 chunks ----------------

__global__ __launch_bounds__(256) void k_pack1(const float* __restrict__ src, long ld,
                                               long zs, int nc,
                                               unsigned short* __restrict__ dst) {
  __shared__ float tile[32][132];
  const float* Sp = src + (long)blockIdx.z * zs;
  int c = blockIdx.x, t = threadIdx.x;
  for (int i = 0; i < 4; i++) {
    int kt = blockIdx.y * 4 + i;
    long k0 = (long)kt * 32, n0 = (long)c * 128;
    {
      int k = t >> 3, nn = (t & 7) * 16;
      const float4* p = (const float4*)(Sp + (k0 + k) * ld + n0 + nn);
#pragma unroll
      for (int j = 0; j < 4; j++) *(float4*)&tile[k][nn + j * 4] = p[j];
    }
    __syncthreads();
    size_t cbase = ((size_t)(blockIdx.z * nc + c) * 64 + kt) * 4096;
#pragma unroll
    for (int uu = 0; uu < 2; uu++) {
      int u = t * 2 + uu;
      int n = u >> 2, qp = u & 3;
      int q = qp ^ ((n ^ (n >> 2)) & 3);
      unsigned short hb[8] __attribute__((aligned(16)));
#pragma unroll
      for (int j = 0; j < 8; j++) hb[j] = f2bf(tile[8 * q + j][n]);
      *(uint4*)(dst + cbase + u * 8) = *(const uint4*)hb;
    }
    __syncthreads();
  }
}

__global__ __launch_bounds__(256) void k_pack2(const float* __restrict__ src, long ld,
                                               long zs, int nc,
                                               unsigned short* __restrict__ dh,
                                               unsigned short* __restrict__ dl) {
  __shared__ float tile[32][132];
  const float* Sp = src + (long)blockIdx.z * zs;
  int c = blockIdx.x, t = threadIdx.x;
  for (int i = 0; i < 4; i++) {
    int kt = blockIdx.y * 4 + i;
    long k0 = (long)kt * 32, n0 = (long)c * 128;
    {
      int k = t >> 3, nn = (t & 7) * 16;
      const float4* p = (const float4*)(Sp + (k0 + k) * ld + n0 + nn);
#pragma unroll
      for (int j = 0; j < 4; j++) *(float4*)&tile[k][nn + j * 4] = p[j];
    }
    __syncthreads();
    size_t cbase = ((size_t)(blockIdx.z * nc + c) * 64 + kt) * 4096;
#pragma unroll
    for (int uu = 0; uu < 2; uu++) {
      int u = t * 2 + uu;
      int n = u >> 2, qp = u & 3;
      int q = qp ^ ((n ^ (n >> 2)) & 3);
      unsigned short hb[8] __attribute__((aligned(16)));
      unsigned short lb[8] __attribute__((aligned(16)));
#pragma unroll
      for (int j = 0; j < 8; j++) split2(tile[8 * q + j][n], hb[j], lb[j]);
      *(uint4*)(dh + cbase + u * 8) = *(const uint4*)hb;
      *(uint4*)(dl + cbase + u * 8) = *(const uint4*)lb;
    }
    __syncthreads();
  }
}

// pack bf16 [z][S][HD] -> chunks [z][64][4096] (8KB B-chunk image: rows=tokens, k=HD)
__global__ __launch_bounds__(256) void k_packbf(const unsigned short* __restrict__ src,
                                                unsigned short* __restrict__ dst) {
  int ttile = blockIdx.x;  // 0..15 (128-token tiles)
  int z = blockIdx.y;      // kv head
  const unsigned short* Sp = src + ((size_t)z * S_LEN + (size_t)ttile * 128) * HD;
  size_t ob = ((size_t)z * 64 + (size_t)ttile * 4) * 4096;
  int t = threadIdx.x;
#pragma unroll
  for (int kst = 0; kst < 4; kst++) {
#pragma unroll
    for (int uu = 0; uu < 2; uu++) {
      int u = t * 2 + uu;
      int n = u >> 2, qp = u & 3;
      int q = qp ^ ((n ^ (n >> 2)) & 3);
      *(uint4*)(dst + ob + (size_t)kst * 4096 + u * 8) =
          *(const uint4*)(Sp + (size_t)n * HD + kst * 32 + q * 8);
    }
  }
}

// ---------------- qkv / wo GEMMs (fp32-emulated, 2-phase pipelined) ----------------

__global__ __launch_bounds__(256) void k_qkv_s(const unsigned short* __restrict__ Ah,
                                               const unsigned short* __restrict__ Al,
                                               const unsigned short* __restrict__ BPh,
                                               const unsigned short* __restrict__ BPl,
                                               float* __restrict__ C) {
  __shared__ unsigned short Ash[2 * 4096], Asl[2 * 4096], Bsh[2 * 4096], Bsl[2 * 4096];
  int row0 = blockIdx.y * 128;
  size_t cb = (size_t)blockIdx.x * 64 * 4096;
  int w = threadIdx.x >> 6;
  int wr = (w >> 1) * 64, wc = (w & 1) * 64;
  uint4 vah[2], val[2];
  loadA2_rows(Ah, DMODEL, row0, 0, vah);
  loadA2_rows(Al, DMODEL, row0, 0, val);
  stageB_chunk(BPh + cb, Bsh);
  stageB_chunk(BPl + cb, Bsl);
  writeA2(vah, Ash);
  writeA2(val, Asl);
  WAIT_ALL;
  BAR;
  f32x4 acc[4][4] = {};
  for (int kt = 0; kt < 64; kt++) {
    int cur = (kt & 1) << 12, nxt = 4096 - cur;
    if (kt + 1 < 64) {
      loadA2_rows(Ah, DMODEL, row0, (kt + 1) * 32, vah);
      loadA2_rows(Al, DMODEL, row0, (kt + 1) * 32, val);
      stageB_chunk(BPh + cb + (size_t)(kt + 1) * 4096, Bsh + nxt);
      stageB_chunk(BPl + cb + (size_t)(kt + 1) * 4096, Bsl + nxt);
    }
    SCHEDBAR;
    mma16_split_reg(Ash + cur, Asl + cur, Bsh + cur, Bsl + cur, wr, wc, acc);
    SCHEDBAR;
    if (kt + 1 < 64) {
      writeA2(vah, Ash + nxt);
      writeA2(val, Asl + nxt);
    }
    WAIT_ALL;
    BAR;
  }
  int col0 = blockIdx.x * 128;
  int l = threadIdx.x & 63;
  int er = wr + ((l >> 4) << 2), ec = wc + (l & 15);
#pragma unroll
  for (int m = 0; m < 4; m++)
#pragma unroll
    for (int n = 0; n < 4; n++)
#pragma unroll
      for (int r = 0; r < 4; r++) {
        float v = acc[m][n][r];
        v = fminf(fmaxf(v, -8.f), 8.f);
        C[(size_t)(row0 + er + m * 16 + r) * QKV_N + col0 + ec + n * 16] = v;
      }
}

__global__ __launch_bounds__(256) void k_wo_s(const unsigned short* __restrict__ Ah,
                                              const unsigned short* __restrict__ Al,
                                              const unsigned short* __restrict__ BPh,
                                              const unsigned short* __restrict__ BPl,
                                              const float* __restrict__ resid,
                                              float* __restrict__ x1) {
  __shared__ unsigned short Ash[2 * 4096], Asl[2 * 4096], Bsh[2 * 4096], Bsl[2 * 4096];
  int row0 = blockIdx.y * 128;
  size_t cb = (size_t)blockIdx.x * 64 * 4096;
  int w = threadIdx.x >> 6;
  int wr = (w >> 1) * 64, wc = (w & 1) * 64;
  uint4 vah[2], val[2];
  loadA2_rows(Ah, DMODEL, row0, 0, vah);
  loadA2_rows(Al, DMODEL, row0, 0, val);
  stageB_chunk(BPh + cb, Bsh);
  stageB_chunk(BPl + cb, Bsl);
  writeA2(vah, Ash);
  writeA2(val, Asl);
  WAIT_ALL;
  BAR;
  f32x4 acc[4][4] = {};
  for (int kt = 0; kt < 64; kt++) {
    int cur = (kt & 1) << 12, nxt = 4096 - cur;
    if (kt + 1 < 64) {
      loadA2_rows(Ah, DMODEL, row0, (kt + 1) * 32, vah);
      loadA2_rows(Al, DMODEL, row0, (kt + 1) * 32, val);
      stageB_chunk(BPh + cb + (size_t)(kt + 1) * 4096, Bsh + nxt);
      stageB_chunk(BPl + cb + (size_t)(kt + 1) * 4096, Bsl + nxt);
    }
    SCHEDBAR;
    mma16_split_reg(Ash + cur, Asl + cur, Bsh + cur, Bsl + cur, wr, wc, acc);
    SCHEDBAR;
    if (kt + 1 < 64) {
      writeA2(vah, Ash + nxt);
      writeA2(val, Asl + nxt);
    }
    WAIT_ALL;
    BAR;
  }
  int col0 = blockIdx.x * 128;
  int l = threadIdx.x & 63;
  int er = wr + ((l >> 4) << 2), ec = wc + (l & 15);
#pragma unroll
  for (int m = 0; m < 4; m++)
#pragma unroll
    for (int n = 0; n < 4; n++)
#pragma unroll
      for (int r = 0; r < 4; r++) {
        size_t idx = (size_t)(row0 + er + m * 16 + r) * DMODEL + col0 + ec + n * 16;
        x1[idx] = resid[idx] + acc[m][n][r];
      }
}

// ---------------- flash attention: barrier-free, L2-direct K/V fragments ----------------
// grid 512 linear; block 128 thr = 2 waves; wave owns 32 Q rows; K/V tiles of 128 tokens.
// XCD-friendly mapping: h = (bid&7) | ((bid>>8)<<3)  (head h on XCD h%8), rt = (bid>>3)&31.

__global__ __launch_bounds__(128) void k_flash(const unsigned short* __restrict__ qh,
                                               const unsigned short* __restrict__ ql,
                                               const unsigned short* __restrict__ kPh,
                                               const unsigned short* __restrict__ kPl,
                                               const unsigned short* __restrict__ vPh,
                                               const unsigned short* __restrict__ vPl,
                                               unsigned short* __restrict__ ath,
                                               unsigned short* __restrict__ atl) {
  int bid = blockIdx.x;
  int h = (bid & 7) | ((bid >> 8) << 3);
  int rt = (bid >> 3) & 31;
  int kv = h >> 2;
  int ntiles = (rt >> 1) + 1;
  __shared__ float Pds[2][32 * 132];  // per-wave P scratch, padded stride
  int t = threadIdx.x;
  int w = t >> 6, l = t & 63;
  int lr = l & 15, lg = l >> 4;
  int qoff = ((lg ^ ((lr ^ (lr >> 2)) & 3)) << 3);
  int wrow0 = rt * 64 + w * 32;
  const unsigned short* Qbh = qh + (size_t)h * S_LEN * HD;
  const unsigned short* Qbl = ql + (size_t)h * S_LEN * HD;
  const unsigned short* Kch = kPh + (size_t)kv * 64 * 4096;
  const unsigned short* Kcl = kPl + (size_t)kv * 64 * 4096;
  const unsigned short* Vch = vPh + (size_t)kv * 64 * 4096;
  const unsigned short* Vcl = vPl + (size_t)kv * 64 * 4096;
  float* Pw = &Pds[w][0];
  float mrun[2][4], lrun[2][4];
  f32x4 Oc[2][8];
#pragma unroll
  for (int m = 0; m < 2; m++)
#pragma unroll
    for (int r = 0; r < 4; r++) { mrun[m][r] = -3.4e38f; lrun[m][r] = 0.f; }
#pragma unroll
  for (int m = 0; m < 2; m++)
#pragma unroll
    for (int n = 0; n < 8; n++)
#pragma unroll
      for (int r = 0; r < 4; r++) Oc[m][n][r] = 0.f;
  const float scale = 0.08838834764831845f;  // 1/sqrt(128)

  for (int kt = 0; kt < ntiles; kt++) {
    f32x4 Sa[2][8];
#pragma unroll
    for (int m = 0; m < 2; m++)
#pragma unroll
      for (int n = 0; n < 8; n++)
#pragma unroll
        for (int r = 0; r < 4; r++) Sa[m][n][r] = 0.f;
    // ---- QK^T: K fragments straight from packed global chunks (L2-hot) ----
#pragma unroll
    for (int kst = 0; kst < 4; kst++) {
      short8 qfh[2], qfl[2];
#pragma unroll
      for (int m = 0; m < 2; m++) {
        size_t o = (size_t)(wrow0 + m * 16 + lr) * HD + kst * 32 + lg * 8;
        qfh[m] = *(const short8*)(Qbh + o);
        qfl[m] = *(const short8*)(Qbl + o);
      }
      const unsigned short* Kh = Kch + (size_t)(kt * 4 + kst) * 4096;
      const unsigned short* Kl = Kcl + (size_t)(kt * 4 + kst) * 4096;
      short8 bh[8], bl[8];
#pragma unroll
      for (int n = 0; n < 8; n++) {
        bh[n] = *(const short8*)(Kh + (n * 16 + lr) * 32 + qoff);
        bl[n] = *(const short8*)(Kl + (n * 16 + lr) * 32 + qoff);
      }
#pragma unroll
      for (int m = 0; m < 2; m++)
#pragma unroll
        for (int n = 0; n < 8; n++) {
          Sa[m][n] = __builtin_amdgcn_mfma_f32_16x16x32_bf16(qfh[m], bh[n], Sa[m][n], 0, 0, 0);
          Sa[m][n] = __builtin_amdgcn_mfma_f32_16x16x32_bf16(qfh[m], bl[n], Sa[m][n], 0, 0, 0);
          Sa[m][n] = __builtin_amdgcn_mfma_f32_16x16x32_bf16(qfl[m], bh[n], Sa[m][n], 0, 0, 0);
        }
    }
    // ---- online softmax (intra-wave; rows in (m,lg,r), cols in (n,lr)) ----
#pragma unroll
    for (int m = 0; m < 2; m++)
#pragma unroll
      for (int r = 0; r < 4; r++) {
        int row = wrow0 + m * 16 + lg * 4 + r;
        float mx = mrun[m][r];
#pragma unroll
        for (int n = 0; n < 8; n++) {
          float v = Sa[m][n][r] * scale;
          int col = kt * 128 + n * 16 + lr;
          v = (col <= row) ? v : -3.4e38f;
          Sa[m][n][r] = v;
          mx = fmaxf(mx, v);
        }
        mx = fmaxf(mx, __shfl_xor(mx, 1));
        mx = fmaxf(mx, __shfl_xor(mx, 2));
        mx = fmaxf(mx, __shfl_xor(mx, 4));
        mx = fmaxf(mx, __shfl_xor(mx, 8));
        float al_ = expf(mrun[m][r] - mx);
        float sum = 0.f;
#pragma unroll
        for (int n = 0; n < 8; n++) {
          float v = Sa[m][n][r];
          float e = (v > -1.0e37f) ? expf(v - mx) : 0.f;
          Sa[m][n][r] = e;
          sum += e;
        }
        sum += __shfl_xor(sum, 1);
        sum += __shfl_xor(sum, 2);
        sum += __shfl_xor(sum, 4);
        sum += __shfl_xor(sum, 8);
        lrun[m][r] = lrun[m][r] * al_ + sum;
        mrun[m][r] = mx;
#pragma unroll
        for (int n = 0; n < 8; n++) Oc[m][n][r] *= al_;
      }
    // ---- P transpose through per-wave LDS (f32, padded) ----
    WAIT_LDS;   // WAR: prior tile's PV reads done
    SCHEDBAR;
#pragma unroll
    for (int m = 0; m < 2; m++)
#pragma unroll
      for (int n = 0; n < 8; n++)
#pragma unroll
        for (int r = 0; r < 4; r++)
          Pw[(m * 16 + lg * 4 + r) * 132 + n * 16 + lr] = Sa[m][n][r];
    WAIT_LDS;   // RAW: all P writes visible before reads
    SCHEDBAR;
    // ---- PV: V fragments straight from packed global chunks; P split on read ----
#pragma unroll
    for (int kst = 0; kst < 4; kst++) {
      const unsigned short* Vh = Vch + (size_t)(kt * 4 + kst) * 4096;
      const unsigned short* Vl = Vcl + (size_t)(kt * 4 + kst) * 4096;
      short8 bh[8], bl[8];
#pragma unroll
      for (int n = 0; n < 8; n++) {
        bh[n] = *(const short8*)(Vh + (n * 16 + lr) * 32 + qoff);
        bl[n] = *(const short8*)(Vl + (n * 16 + lr) * 32 + qoff);
      }
#pragma unroll
      for (int m = 0; m < 2; m++) {
        const float* pp = &Pw[(m * 16 + lr) * 132 + kst * 32 + lg * 8];
        unsigned short ahb[8] __attribute__((aligned(16)));
        unsigned short alb[8] __attribute__((aligned(16)));
#pragma unroll
        for (int j = 0; j < 8; j++) split2(pp[j], ahb[j], alb[j]);
        short8 ah = *(const short8*)ahb;
        short8 al_ = *(const short8*)alb;
#pragma unroll
        for (int n = 0; n < 8; n++) {
          Oc[m][n] = __builtin_amdgcn_mfma_f32_16x16x32_bf16(ah, bh[n], Oc[m][n], 0, 0, 0);
          Oc[m][n] = __builtin_amdgcn_mfma_f32_16x16x32_bf16(ah, bl[n], Oc[m][n], 0, 0, 0);
          Oc[m][n] = __builtin_amdgcn_mfma_f32_16x16x32_bf16(al_, bh[n], Oc[m][n], 0, 0, 0);
        }
      }
    }
  }
  // ---- epilogue: O / l -> split bf16 -> global ----
#pragma unroll
  for (int m = 0; m < 2; m++)
#pragma unroll
    for (int r = 0; r < 4; r++) {
      size_t row = wrow0 + m * 16 + lg * 4 + r;
      float lv = lrun[m][r];
#pragma unroll
      for (int n = 0; n < 8; n++) {
        unsigned short hh, ll;
        split2(Oc[m][n][r] / lv, hh, ll);
        size_t o = row * DMODEL + (size_t)h * HD + n * 16 + lr;
        ath[o] = hh;
        atl[o] = ll;
      }
    }
}

// ---------------- MoE GEMMs: fused up-proj + down-proj, 2-phase pipelined ----------------

__global__ __launch_bounds__(256) void k_moe1f(const unsigned short* __restrict__ h2b,
                                               const unsigned short* __restrict__ wPa,
                                               const unsigned short* __restrict__ wPb,
                                               const int* __restrict__ off,
                                               const int* __restrict__ ptok,
                                               const int* __restrict__ meta,
                                               unsigned short* __restrict__ g) {
  int ty = blockIdx.y;
  if (ty >= meta[25]) return;
  int tt = meta[26 + ty];
  int e = tt & 7, m0 = tt >> 3;
  int nvalid = min(128, meta[e] - m0);
  const int* toks = ptok + off[e] + m0;
  const unsigned short* B1 = wPa + (size_t)(e * 16 + blockIdx.x) * 64 * 4096;
  const unsigned short* B2 = wPb + (size_t)(e * 16 + blockIdx.x) * 64 * 4096;
  __shared__ unsigned short As[2 * 4096], Bs1[2 * 4096], Bs2[2 * 4096];
  int w = threadIdx.x >> 6;
  int wr = (w >> 1) * 64, wc = (w & 1) * 64;
  uint4 va[2];
  loadA2_g(h2b, DMODEL, toks, nvalid, 0, va);
  stageB_chunk(B1, Bs1);
  stageB_chunk(B2, Bs2);
  writeA2(va, As);
  WAIT_ALL;
  BAR;
  f32x4 acc1[4][4] = {}, acc2[4][4] = {};
  for (int kt = 0; kt < 64; kt++) {
    int cur = (kt & 1) << 12, nxt = 4096 - cur;
    if (kt + 1 < 64) {
      loadA2_g(h2b, DMODEL, toks, nvalid, (kt + 1) * 32, va);
      stageB_chunk(B1 + (size_t)(kt + 1) * 4096, Bs1 + nxt);
      stageB_chunk(B2 + (size_t)(kt + 1) * 4096, Bs2 + nxt);
    }
    SCHEDBAR;
    mma16_dualB(As + cur, Bs1 + cur, Bs2 + cur, wr, wc, acc1, acc2);
    SCHEDBAR;
    if (kt + 1 < 64) writeA2(va, As + nxt);
    WAIT_ALL;
    BAR;
  }
  int col0 = blockIdx.x * 128;
  int l = threadIdx.x & 63;
  int er = wr + ((l >> 4) << 2), ec = wc + (l & 15);
  size_t gbase = (size_t)off[e] + m0;
#pragma unroll
  for (int m = 0; m < 4; m++)
#pragma unroll
    for (int n = 0; n < 4; n++)
#pragma unroll
      for (int r = 0; r < 4; r++) {
        int rl = er + m * 16 + r;
        if (rl < nvalid) {
          float a = acc1[m][n][r];
          float s = a / (1.f + expf(-a));
          g[(gbase + rl) * FF + col0 + ec + n * 16] = f2bf(s * acc2[m][n][r]);
        }
      }
}

__global__ __launch_bounds__(256) void k_moe2(const unsigned short* __restrict__ g,
                                              const unsigned short* __restrict__ wP,
                                              const int* __restrict__ off,
                                              const int* __restrict__ ptok,
                                              const float* __restrict__ pw,
                                              const int* __restrict__ meta,
                                              float* __restrict__ y) {
  int ty = blockIdx.y;
  if (ty >= meta[25]) return;
  int tt = meta[26 + ty];
  int e = tt & 7, m0 = tt >> 3;
  int nvalid = min(128, meta[e] - m0);
  long pbase = (long)off[e] + m0;
  const unsigned short* Bb = wP + (size_t)(e * 16 + blockIdx.x) * 64 * 4096;
  __shared__ unsigned short As[2 * 4096], Bs[2 * 4096];
  int w = threadIdx.x >> 6;
  int wr = (w >> 1) * 64, wc = (w & 1) * 64;
  uint4 va[2];
  loadA2_rows(g, FF, pbase, 0, va);
  stageB_chunk(Bb, Bs);
  writeA2(va, As);
  WAIT_ALL;
  BAR;
  f32x4 acc[4][4] = {};
  for (int kt = 0; kt < 64; kt++) {
    int cur = (kt & 1) << 12, nxt = 4096 - cur;
    if (kt + 1 < 64) {
      loadA2_rows(g, FF, pbase, (kt + 1) * 32, va);
      stageB_chunk(Bb + (size_t)(kt + 1) * 4096, Bs + nxt);
    }
    SCHEDBAR;
    mma16(As + cur, Bs + cur, wr, wc, acc);
    SCHEDBAR;
    if (kt + 1 < 64) writeA2(va, As + nxt);
    WAIT_ALL;
    BAR;
  }
  int col0 = blockIdx.x * 128;
  int l = threadIdx.x & 63;
  int er = wr + ((l >> 4) << 2), ec = wc + (l & 15);
#pragma unroll
  for (int m = 0; m < 4; m++)
#pragma unroll
    for (int n = 0; n < 4; n++)
#pragma unroll
      for (int r = 0; r < 4; r++) {
        int rl = er + m * 16 + r;
        if (rl < nvalid) {
          long p = pbase + rl;
          int tk = ptok[p];
          atomicAdd(&y[(size_t)tk * DMODEL + col0 + ec + n * 16], acc[m][n][r] * pw[p]);
        }
      }
}

// ---------------- small kernels ----------------

__global__ __launch_bounds__(256) void k_ln(const float* __restrict__ x,
                                            const float* __restrict__ w,
                                            unsigned short* __restrict__ obh,
                                            unsigned short* __restrict__ obl,
                                            float* __restrict__ of) {
  int row = blockIdx.x;
  const float* xr = x + (size_t)row * DMODEL;
  float s = 0.f, ss = 0.f;
  for (int c = threadIdx.x; c < DMODEL; c += 256) {
    float v = xr[c];
    s += v; ss += v * v;
  }
#pragma unroll
  for (int o = 32; o; o >>= 1) { s += __shfl_down(s, o); ss += __shfl_down(ss, o); }
  __shared__ float rs[4], rss[4], mu_s, inv_s;
  int wid = threadIdx.x >> 6;
  if ((threadIdx.x & 63) == 0) { rs[wid] = s; rss[wid] = ss; }
  __syncthreads();
  if (threadIdx.x == 0) {
    float S1 = rs[0] + rs[1] + rs[2] + rs[3];
    float S2 = rss[0] + rss[1] + rss[2] + rss[3];
    float mu = S1 / DMODEL;
    mu_s = mu;
    inv_s = rsqrtf(S2 / DMODEL - mu * mu + 1e-5f);
  }
  __syncthreads();
  float mu = mu_s, inv = inv_s;
  for (int c = threadIdx.x; c < DMODEL; c += 256) {
    float v = (xr[c] - mu) * inv * w[c];
    unsigned short hh, ll;
    split2(v, hh, ll);
    obh[(size_t)row * DMODEL + c] = hh;
    if (obl) obl[(size_t)row * DMODEL + c] = ll;
    if (of) of[(size_t)row * DMODEL + c] = v;
  }
}

__global__ void k_rope2(const float* __restrict__ qkv, unsigned short* __restrict__ qh,
                        unsigned short* __restrict__ ql, unsigned short* __restrict__ kh,
                        unsigned short* __restrict__ kl) {
  int t = blockIdx.x;
  int d = threadIdx.x;  // 0..63
  float pf = (float)pow(500000.0, (double)d * (1.0 / 64.0));
  float invf = 1.0f / pf;
  float ang = (float)t * invf;
  float cs = (float)cos((double)ang);
  float sn = (float)sin((double)ang);
  const float* row = qkv + (size_t)t * QKV_N;
  unsigned short hh, ll;
#pragma unroll
  for (int hq = 0; hq < NH; hq++) {
    float a = row[hq * HD + d], b = row[hq * HD + d + 64];
    size_t base = ((size_t)hq * S_LEN + t) * HD;
    split2(a * cs - b * sn, hh, ll); qh[base + d] = hh; ql[base + d] = ll;
    split2(b * cs + a * sn, hh, ll); qh[base + d + 64] = hh; ql[base + d + 64] = ll;
  }
#pragma unroll
  for (int kv = 0; kv < NKV; kv++) {
    float a = row[NH * HD + kv * HD + d], b = row[NH * HD + kv * HD + d + 64];
    size_t base = ((size_t)kv * S_LEN + t) * HD;
    split2(a * cs - b * sn, hh, ll); kh[base + d] = hh; kl[base + d] = ll;
    split2(b * cs + a * sn, hh, ll); kh[base + d + 64] = hh; kl[base + d + 64] = ll;
  }
}

__global__ __launch_bounds__(256) void k_router(const float* __restrict__ h2,
                                                const float* __restrict__ rw,
                                                int* __restrict__ topi,
                                                float* __restrict__ topw,
                                                int* __restrict__ cnt) {
  int t = blockIdx.x;
  __shared__ float hs[DMODEL];
  __shared__ float lg[NE];
  for (int c = threadIdx.x; c < DMODEL; c += 256) hs[c] = h2[(size_t)t * DMODEL + c];
  __syncthreads();
  int grp = threadIdx.x >> 5;
  int ln = threadIdx.x & 31;
  float p = 0.f;
  for (int c = ln; c < DMODEL; c += 32) p += hs[c] * rw[(size_t)grp * DMODEL + c];
#pragma unroll
  for (int o = 16; o; o >>= 1) p += __shfl_down(p, o, 32);
  if (ln == 0) lg[grp] = p;
  __syncthreads();
  if (threadIdx.x == 0) {
    float l0 = -3.4e38f; int i0 = 0;
    for (int e = 0; e < NE; e++)
      if (lg[e] > l0) { l0 = lg[e]; i0 = e; }
    float l1 = -3.4e38f; int i1 = 0;
    for (int e = 0; e < NE; e++)
      if (e != i0 && lg[e] > l1) { l1 = lg[e]; i1 = e; }
    float z = expf(l1 - l0);
    topi[t * 2] = i0; topi[t * 2 + 1] = i1;
    topw[t * 2] = 1.f / (1.f + z); topw[t * 2 + 1] = z / (1.f + z);
    atomicAdd(&cnt[i0], 1);
    atomicAdd(&cnt[i1], 1);
  }
}

__global__ void k_scan(int* __restrict__ meta) {
  if (threadIdx.x == 0 && blockIdx.x == 0) {
    int o = 0, nt = 0;
    for (int e = 0; e < NE; e++) {
      meta[16 + e] = o;
      for (int m0 = 0; m0 < meta[e]; m0 += 128) meta[26 + nt++] = (m0 << 3) | e;
      o += meta[e];
    }
    meta[24] = o;
    meta[25] = nt;
  }
}

__global__ void k_fill(const int* __restrict__ topi, const float* __restrict__ topw,
                       int* __restrict__ meta, int* __restrict__ ptok,
                       float* __restrict__ pw) {
  int t = blockIdx.x * blockDim.x + threadIdx.x;
  if (t >= S_LEN) return;
#pragma unroll
  for (int j = 0; j < 2; j++) {
    int e = topi[t * 2 + j];
    int p = atomicAdd(&meta[8 + e], 1);
    ptok[meta[16 + e] + p] = t;
    pw[meta[16 + e] + p] = topw[t * 2 + j];
  }
}

// out += y (in place; out holds x1)
__global__ void k_final(float* __restrict__ out, const float* __restrict__ y) {
  int i = blockIdx.x * blockDim.x + threadIdx.x;
  float4 a = ((const float4*)out)[i];
  float4 b = ((const float4*)y)[i];
  ((float4*)out)[i] = make_float4(a.x + b.x, a.y + b.y, a.z + b.z, a.w + b.w);
}

// ---------------- launch ----------------

extern "C" void kernel_launch(void* const* d_in, const int* in_sizes, int n_in,
                              void* d_out, int out_size, void* d_ws, size_t ws_size,
                              hipStream_t stream) {
  (void)in_sizes; (void)n_in; (void)out_size; (void)ws_size;
  const float* x = (const float*)d_in[0];
  const float* ln1w = (const float*)d_in[2];
  const float* ln2w = (const float*)d_in[3];
  const float* wqkv = (const float*)d_in[4];
  const float* wo = (const float*)d_in[5];
  const float* rw = (const float*)d_in[6];
  const float* w1 = (const float*)d_in[7];
  const float* v1 = (const float*)d_in[8];
  const float* w2 = (const float*)d_in[9];
  float* out = (float*)d_out;  // holds x1 after k_wo_s

  char* wsb = (char*)d_ws;
  const size_t MiB = 1u << 20;
  // ---- attention phase ----
  unsigned short* h1h = (unsigned short*)(wsb + 0 * MiB);      // 8
  unsigned short* h1l = (unsigned short*)(wsb + 8 * MiB);      // 8
  float* qkvb = (float*)(wsb + 16 * MiB);                      // 24
  unsigned short* qh = (unsigned short*)(wsb + 40 * MiB);      // 8
  unsigned short* ql = (unsigned short*)(wsb + 48 * MiB);      // 8
  unsigned short* kh = (unsigned short*)(wsb + 56 * MiB);      // 2
  unsigned short* kl = (unsigned short*)(wsb + 58 * MiB);      // 2
  unsigned short* vPh = (unsigned short*)(wsb + 60 * MiB);     // 2
  unsigned short* vPl = (unsigned short*)(wsb + 62 * MiB);     // 2
  unsigned short* kPh = (unsigned short*)(wsb + 64 * MiB);     // 2
  unsigned short* kPl = (unsigned short*)(wsb + 66 * MiB);     // 2
  unsigned short* ath = (unsigned short*)(wsb + 68 * MiB);     // 8
  unsigned short* atl = (unsigned short*)(wsb + 76 * MiB);     // 8
  unsigned short* wqkvPh = (unsigned short*)(wsb + 84 * MiB);  // 12
  unsigned short* wqkvPl = (unsigned short*)(wsb + 96 * MiB);  // 12
  unsigned short* woPh = (unsigned short*)(wsb + 108 * MiB);   // 8
  unsigned short* woPl = (unsigned short*)(wsb + 116 * MiB);   // 8
  // ---- MoE phase (over dead attention buffers) ----
  float* h2f = (float*)(wsb + 0 * MiB);                        // 16 (over h1)
  unsigned short* h2b = (unsigned short*)(wsb + 16 * MiB);     // 8 (over qkvb)
  unsigned short* g = (unsigned short*)(wsb + 24 * MiB);       // 16 (over qkvb)
  float* y = (float*)(wsb + 40 * MiB);                         // 16 (over qh/ql)
  unsigned short* wPa = (unsigned short*)(wsb + 56 * MiB);     // 64 (over k/vP/kP/at/wqkvP)
  unsigned short* wPb = (unsigned short*)(wsb + 120 * MiB);    // 64
  char* small = wsb + 184 * MiB;
  int* topi = (int*)small;
  float* topw = (float*)(small + 16384);
  int* ptok = (int*)(small + 32768);
  float* pw = (float*)(small + 49152);
  int* meta = (int*)(small + 65536);  // 128 ints

  // ---- pack attention weights ----
  k_pack2<<<dim3(QKV_N / 128, 16, 1), 256, 0, stream>>>(wqkv, QKV_N, 0, QKV_N / 128,
                                                        wqkvPh, wqkvPl);
  k_pack2<<<dim3(DMODEL / 128, 16, 1), 256, 0, stream>>>(wo, DMODEL, 0, DMODEL / 128,
                                                         woPh, woPl);

  // ---- attention sublayer (fp32-emulated) ----
  k_ln<<<S_LEN, 256, 0, stream>>>(x, ln1w, h1h, h1l, (float*)nullptr);
  k_qkv_s<<<dim3(QKV_N / 128, S_LEN / 128), 256, 0, stream>>>(h1h, h1l, wqkvPh, wqkvPl, qkvb);
  k_rope2<<<S_LEN, 64, 0, stream>>>(qkvb, qh, ql, kh, kl);
  k_pack2<<<dim3(1, 16, NKV), 256, 0, stream>>>(qkvb + (NH + NKV) * HD, QKV_N, HD, 1,
                                                vPh, vPl);
  k_packbf<<<dim3(16, NKV), 256, 0, stream>>>(kh, kPh);
  k_packbf<<<dim3(16, NKV), 256, 0, stream>>>(kl, kPl);
  k_flash<<<512, 128, 0, stream>>>(qh, ql, kPh, kPl, vPh, vPl, ath, atl);
  k_wo_s<<<dim3(16, 16), 256, 0, stream>>>(ath, atl, woPh, woPl, x, out);

  // ---- MoE sublayer ----
  k_ln<<<S_LEN, 256, 0, stream>>>(out, ln2w, h2b, (unsigned short*)nullptr, h2f);
  hipMemsetAsync(y, 0, (size_t)S_LEN * DMODEL * 4, stream);
  hipMemsetAsync(meta, 0, 512, stream);
  k_router<<<S_LEN, 256, 0, stream>>>(h2f, rw, topi, topw, meta);
  k_scan<<<1, 64, 0, stream>>>(meta);
  k_fill<<<8, 256, 0, stream>>>(topi, topw, meta, ptok, pw);
  k_pack1<<<dim3(16, 16, NE), 256, 0, stream>>>(w1, FF, (long)DMODEL * FF, 16, wPa);
  k_pack1<<<dim3(16, 16, NE), 256, 0, stream>>>(v1, FF, (long)DMODEL * FF, 16, wPb);
  k_moe1f<<<dim3(16, 40), 256, 0, stream>>>(h2b, wPa, wPb, meta + 16, ptok, meta, g);
  k_pack1<<<dim3(16, 16, NE), 256, 0, stream>>>(w2, DMODEL, (long)FF * DMODEL, 16, wPa);
  k_moe2<<<dim3(16, 40), 256, 0, stream>>>(g, wPa, meta + 16, ptok, pw, meta, y);
  k_final<<<(S_LEN * DMODEL / 4) / 256, 256, 0, stream>>>(out, y);
}